// Round 1
// baseline (143.515 us; speedup 1.0000x reference)
//
#include <hip/hip_runtime.h>
#include <hip/hip_bf16.h>

// Block-local matmul: out block (b,i,j)[64x64] = A(b,i,j)[64x64] @ W(i,j)[64x64]
// B=4, M=K=N=4096, BLOCK_NUM=64. Memory-bound (~576 MB HBM floor).

typedef short bf16x8 __attribute__((ext_vector_type(8)));
typedef float f32x4 __attribute__((ext_vector_type(4)));

__device__ __forceinline__ unsigned short f2bf(float f) {
    union { float f; unsigned int u; } v; v.f = f;
    unsigned int u = v.u;
    u += 0x7fffu + ((u >> 16) & 1u);   // round-to-nearest-even
    return (unsigned short)(u >> 16);
}

__global__ __launch_bounds__(256, 4) void block_matmul_kernel(
    const float* __restrict__ x, const float* __restrict__ w,
    float* __restrict__ out) {
    // LDS: A as [m][k] bf16 (128 B rows), W^T as [n][k] bf16; both XOR-swizzled
    __shared__ unsigned short As[64 * 64];
    __shared__ unsigned short Ws[64 * 64];

    // XCD-aware bijective swizzle (nwg = 16384 % 8 == 0): each XCD gets a
    // contiguous chunk; b innermost so the 4 batches sharing W(i,j) are
    // back-to-back on one XCD (W L2-resident for reuse).
    const int nwg   = 4 * 64 * 64;
    const int chunk = nwg >> 3;
    int orig = blockIdx.x;
    int wg   = (orig & 7) * chunk + (orig >> 3);

    int b  = wg & 3;
    int ij = wg >> 2;
    int i  = ij >> 6;
    int j  = ij & 63;

    const float* Ab = x   + ((size_t)b * 4096 + (size_t)i * 64) * 4096 + (size_t)j * 64;
    const float* Wb = w   + ((size_t)i * 64) * 4096 + (size_t)j * 64;
    float*       Ob = out + ((size_t)b * 4096 + (size_t)i * 64) * 4096 + (size_t)j * 64;

    const int t = threadIdx.x;

    // ---- Stage A block: coalesced float4 loads (16 lanes cover one 256B row),
    //      convert to bf16, packed 8B LDS writes, swizzled [m][k] layout.
    #pragma unroll
    for (int it = 0; it < 4; ++it) {
        int idx = it * 256 + t;        // 0..1023
        int m   = idx >> 4;            // row 0..63
        int k4  = (idx & 15) << 2;     // col (floats), multiple of 4
        float4 v = *reinterpret_cast<const float4*>(Ab + (size_t)m * 4096 + k4);
        unsigned long long pk =
            (unsigned long long)f2bf(v.x)        |
            ((unsigned long long)f2bf(v.y) << 16) |
            ((unsigned long long)f2bf(v.z) << 32) |
            ((unsigned long long)f2bf(v.w) << 48);
        int addr = m * 128 + ((k4 * 2) ^ ((m & 7) << 4));
        *reinterpret_cast<unsigned long long*>(reinterpret_cast<char*>(As) + addr) = pk;
    }

    // ---- Stage W block TRANSPOSED: thread reads 4 k-consecutive scalars of
    //      column n (each scalar load is 64 lanes x consecutive n = 256B
    //      coalesced), packs to one b64 LDS write at Ws[n][k..k+3].
    {
        int n  = t & 63;
        int kq = (t >> 6) << 2;        // 0,4,8,12
        #pragma unroll
        for (int it = 0; it < 4; ++it) {
            int kb = it * 16 + kq;
            float f0 = Wb[(size_t)(kb + 0) * 4096 + n];
            float f1 = Wb[(size_t)(kb + 1) * 4096 + n];
            float f2 = Wb[(size_t)(kb + 2) * 4096 + n];
            float f3 = Wb[(size_t)(kb + 3) * 4096 + n];
            unsigned long long pk =
                (unsigned long long)f2bf(f0)        |
                ((unsigned long long)f2bf(f1) << 16) |
                ((unsigned long long)f2bf(f2) << 32) |
                ((unsigned long long)f2bf(f3) << 48);
            int addr = n * 128 + ((kb * 2) ^ ((n & 7) << 4));
            *reinterpret_cast<unsigned long long*>(reinterpret_cast<char*>(Ws) + addr) = pk;
        }
    }

    __syncthreads();

    // ---- MFMA: 4 waves, wave wv computes output rows [wv*16, wv*16+16) x 64 cols.
    // mfma_f32_16x16x32_bf16: A lane layout m=l&15, k=(l>>4)*8+e (contig k ✓);
    // B lane layout n=l&15, k=(l>>4)*8+e; D: col=l&15, row=(l>>4)*4+r (m89-verified).
    const int l  = t & 63;
    const int wv = t >> 6;
    const int lr = l & 15;
    const int lk = l >> 4;

    f32x4 acc[4] = {{0.f,0.f,0.f,0.f},{0.f,0.f,0.f,0.f},
                    {0.f,0.f,0.f,0.f},{0.f,0.f,0.f,0.f}};

    #pragma unroll
    for (int kt = 0; kt < 2; ++kt) {
        int kbyte = kt * 64 + lk * 16;             // 16B-aligned
        int am = wv * 16 + lr;
        bf16x8 af = *reinterpret_cast<const bf16x8*>(
            reinterpret_cast<const char*>(As) + am * 128 + (kbyte ^ ((am & 7) << 4)));
        #pragma unroll
        for (int nt = 0; nt < 4; ++nt) {
            int bn = nt * 16 + lr;
            bf16x8 bfr = *reinterpret_cast<const bf16x8*>(
                reinterpret_cast<const char*>(Ws) + bn * 128 + (kbyte ^ ((bn & 7) << 4)));
            acc[nt] = __builtin_amdgcn_mfma_f32_16x16x32_bf16(af, bfr, acc[nt], 0, 0, 0);
        }
    }

    // ---- Epilogue: scalar stores; per (nt,r) the 16-lane groups each write a
    //      64B-aligned contiguous 64B segment — fully coalesced.
    #pragma unroll
    for (int nt = 0; nt < 4; ++nt) {
        #pragma unroll
        for (int r = 0; r < 4; ++r) {
            int orow = wv * 16 + lk * 4 + r;
            int ocol = nt * 16 + lr;
            Ob[(size_t)orow * 4096 + ocol] = acc[nt][r];
        }
    }
}

extern "C" void kernel_launch(void* const* d_in, const int* in_sizes, int n_in,
                              void* d_out, int out_size, void* d_ws, size_t ws_size,
                              hipStream_t stream) {
    const float* x = (const float*)d_in[0];   // [4, 4096, 4096] fp32
    const float* w = (const float*)d_in[1];   // [4096, 4096] fp32
    float* out = (float*)d_out;               // [4, 4096, 4096] fp32

    dim3 grid(4 * 64 * 64);
    dim3 block(256);
    block_matmul_kernel<<<grid, block, 0, stream>>>(x, w, out);
}

// Round 2
// 123.934 us; speedup vs baseline: 1.1580x; 1.1580x over previous
//
#include <hip/hip_runtime.h>
#include <hip/hip_bf16.h>

// Block-local matmul: out block (b,i,j)[64x64] = A(b,i,j)[64x64] @ W(i,j)[64x64]
// B=4, M=K=N=4096, BLOCK_NUM=64. Memory-bound (~576 MB HBM floor ≈ 91 us).
// Round 2: j-inner streaming order, 2 j-blocks per wg (512B runs), dwordx4
// stores via LDS bounce.

typedef short bf16x8 __attribute__((ext_vector_type(8)));
typedef float f32x4 __attribute__((ext_vector_type(4)));

__device__ __forceinline__ unsigned short f2bf(float f) {
    union { float f; unsigned int u; } v; v.f = f;
    unsigned int u = v.u;
    u += 0x7fffu + ((u >> 16) & 1u);   // round-to-nearest-even
    return (unsigned short)(u >> 16);
}

__global__ __launch_bounds__(256, 5) void block_matmul_kernel(
    const float* __restrict__ x, const float* __restrict__ w,
    float* __restrict__ out) {
    // 32 KB LDS: As [64][128] bf16 (256B rows) + Ws [128][64] bf16 (n-major,
    // 128B rows), both XOR-swizzled. Epilogue aliases the whole 32 KB as
    // Os [64][128] f32 for the dwordx4 store bounce.
    __shared__ char smem[32768];
    unsigned short* As = reinterpret_cast<unsigned short*>(smem);
    unsigned short* Ws = reinterpret_cast<unsigned short*>(smem + 16384);
    float*          Os = reinterpret_cast<float*>(smem);

    // Workgroup order: q (j-pair) innermost, then i, then b. XCD-chunked so
    // each XCD streams one contiguous 64 MB slab of x/out; the 4 batches'
    // copies of each W slab run concurrently on different XCDs -> W served
    // once from HBM via L3.
    const int chunk = 8192 >> 3;                 // 1024
    int orig = blockIdx.x;
    int wg   = (orig & 7) * chunk + (orig >> 3);

    int b = wg >> 11;          // 0..3
    int i = (wg >> 5) & 63;    // 0..63
    int q = wg & 31;           // j-pair 0..31  (j = 2q, 2q+1)

    const float* Ab = x   + ((size_t)(b * 4096 + i * 64)) * 4096 + q * 128;
    const float* Wb = w   + ((size_t)(i * 64)) * 4096 + q * 128;
    float*       Ob = out + ((size_t)(b * 4096 + i * 64)) * 4096 + q * 128;

    const int t = threadIdx.x;

    // ---- Stage A tile (64 rows x 128 cols fp32): float4 loads, 512B
    //      contiguous per 2 rows per instruction; bf16 pack, b64 LDS writes.
    #pragma unroll
    for (int it = 0; it < 8; ++it) {
        int idx = it * 256 + t;          // 0..2047
        int m   = idx >> 5;              // row 0..63
        int k4  = (idx & 31) << 2;       // float col, multiple of 4
        float4 v = *reinterpret_cast<const float4*>(Ab + (size_t)m * 4096 + k4);
        unsigned long long pk =
            (unsigned long long)f2bf(v.x)         |
            ((unsigned long long)f2bf(v.y) << 16) |
            ((unsigned long long)f2bf(v.z) << 32) |
            ((unsigned long long)f2bf(v.w) << 48);
        int addr = m * 256 + ((k4 * 2) ^ ((m & 7) << 4));
        *reinterpret_cast<unsigned long long*>(smem + addr) = pk;
    }

    // ---- Stage W tile TRANSPOSED (64 c-rows x 128 n-cols -> Ws[n][c]):
    //      scalar dword loads, 256B coalesced per instruction; 4 consecutive
    //      c packed per b64 LDS write.
    {
        int n  = t & 127;
        int c0 = (t >> 7) << 2;          // 0 or 4
        #pragma unroll
        for (int it = 0; it < 8; ++it) {
            int c = it * 8 + c0;
            float f0 = Wb[(size_t)(c + 0) * 4096 + n];
            float f1 = Wb[(size_t)(c + 1) * 4096 + n];
            float f2 = Wb[(size_t)(c + 2) * 4096 + n];
            float f3 = Wb[(size_t)(c + 3) * 4096 + n];
            unsigned long long pk =
                (unsigned long long)f2bf(f0)         |
                ((unsigned long long)f2bf(f1) << 16) |
                ((unsigned long long)f2bf(f2) << 32) |
                ((unsigned long long)f2bf(f3) << 48);
            int addr = n * 128 + ((c * 2) ^ ((n & 7) << 4));
            *reinterpret_cast<unsigned long long*>(
                reinterpret_cast<char*>(Ws) + addr) = pk;
        }
    }

    __syncthreads();

    // ---- MFMA: 4 waves; wave wv owns output rows [wv*16, wv*16+16) x 128.
    // Per block jj in {0,1}: out_jj = A[:, jj*64..] @ W_jj (contract c=0..63).
    const int l  = t & 63;
    const int wv = t >> 6;
    const int lr = l & 15;
    const int lk = l >> 4;

    f32x4 acc[8];
    #pragma unroll
    for (int z = 0; z < 8; ++z) acc[z] = (f32x4){0.f, 0.f, 0.f, 0.f};

    const int am = wv * 16 + lr;
    #pragma unroll
    for (int jj = 0; jj < 2; ++jj) {
        #pragma unroll
        for (int kt = 0; kt < 2; ++kt) {
            int kbA = jj * 128 + kt * 64 + lk * 16;    // byte col in As row
            bf16x8 af = *reinterpret_cast<const bf16x8*>(
                smem + am * 256 + (kbA ^ ((am & 7) << 4)));
            int kbB = kt * 64 + lk * 16;               // byte col in Ws row
            #pragma unroll
            for (int nt = 0; nt < 4; ++nt) {
                int bn = jj * 64 + nt * 16 + lr;
                bf16x8 bfr = *reinterpret_cast<const bf16x8*>(
                    reinterpret_cast<const char*>(Ws) + bn * 128 +
                    (kbB ^ ((bn & 7) << 4)));
                acc[jj * 4 + nt] =
                    __builtin_amdgcn_mfma_f32_16x16x32_bf16(af, bfr,
                                                            acc[jj * 4 + nt],
                                                            0, 0, 0);
            }
        }
    }

    // ---- Epilogue: bounce acc through LDS (aliases As/Ws) to emit dwordx4
    //      stores (512B contiguous per 2 rows per instruction).
    __syncthreads();    // all MFMA LDS reads done before overwrite

    #pragma unroll
    for (int fn = 0; fn < 8; ++fn) {
        #pragma unroll
        for (int r = 0; r < 4; ++r) {
            int row = wv * 16 + lk * 4 + r;
            int col = fn * 16 + lr;
            Os[row * 128 + (col ^ ((row & 7) << 2))] = acc[fn][r];
        }
    }

    __syncthreads();

    #pragma unroll
    for (int it = 0; it < 8; ++it) {
        int idx = it * 256 + t;
        int row = idx >> 5;
        int c4  = (idx & 31) << 2;
        int col = c4 ^ ((row & 7) << 2);   // xor of multiples of 4: f32x4 stays aligned
        f32x4 v = *reinterpret_cast<const f32x4*>(Os + row * 128 + col);
        *reinterpret_cast<f32x4*>(Ob + (size_t)row * 4096 + c4) = v;
    }
}

extern "C" void kernel_launch(void* const* d_in, const int* in_sizes, int n_in,
                              void* d_out, int out_size, void* d_ws, size_t ws_size,
                              hipStream_t stream) {
    const float* x = (const float*)d_in[0];   // [4, 4096, 4096] fp32
    const float* w = (const float*)d_in[1];   // [4096, 4096] fp32
    float* out = (float*)d_out;               // [4, 4096, 4096] fp32

    dim3 grid(8192);
    dim3 block(256);
    block_matmul_kernel<<<grid, block, 0, stream>>>(x, w, out);
}

// Round 3
// 123.451 us; speedup vs baseline: 1.1625x; 1.0039x over previous
//
#include <hip/hip_runtime.h>
#include <hip/hip_bf16.h>

// Block-local matmul: out block (b,i,j)[64x64] = A(b,i,j)[64x64] @ W(i,j)[64x64]
// B=4, M=K=N=4096, BLOCK_NUM=64. Memory-bound (~576 MB HBM floor ≈ 85-90 us).
// Round 3: register-batched staging (40 loads in flight per wave) to fix
// latency-bound staging (round-1 VGPR=20 proved per-load serialization).

typedef short bf16x8 __attribute__((ext_vector_type(8)));
typedef float f32x4 __attribute__((ext_vector_type(4)));

__device__ __forceinline__ unsigned short f2bf(float f) {
    union { float f; unsigned int u; } v; v.f = f;
    unsigned int u = v.u;
    u += 0x7fffu + ((u >> 16) & 1u);   // round-to-nearest-even
    return (unsigned short)(u >> 16);
}

__global__ __launch_bounds__(256, 4) void block_matmul_kernel(
    const float* __restrict__ x, const float* __restrict__ w,
    float* __restrict__ out) {
    // 32 KB LDS: As [64][128] bf16 (256B rows) + Ws [128][64] bf16 (n-major,
    // 128B rows), both XOR-swizzled. Epilogue aliases the whole 32 KB as
    // Os [64][128] f32 for the dwordx4 store bounce.
    __shared__ char smem[32768];
    unsigned short* Ws = reinterpret_cast<unsigned short*>(smem + 16384);
    float*          Os = reinterpret_cast<float*>(smem);

    // Workgroup order: q (j-pair) innermost, then i, then b. XCD-chunked so
    // each XCD streams one contiguous 64 MB slab of x/out; the 4 batches'
    // copies of each W slab run concurrently on different XCDs -> W served
    // once from HBM via L3.
    const int chunk = 8192 >> 3;                 // 1024
    int orig = blockIdx.x;
    int wg   = (orig & 7) * chunk + (orig >> 3);

    int b = wg >> 11;          // 0..3
    int i = (wg >> 5) & 63;    // 0..63
    int q = wg & 31;           // j-pair 0..31  (j = 2q, 2q+1)

    const float* Ab = x   + ((size_t)(b * 4096 + i * 64)) * 4096 + q * 128;
    const float* Wb = w   + ((size_t)(i * 64)) * 4096 + q * 128;
    float*       Ob = out + ((size_t)(b * 4096 + i * 64)) * 4096 + q * 128;

    const int t = threadIdx.x;

    // ================= Phase 1: batched global loads (pure loads, no waits)
    // A tile 64x128 f32: 8 x float4 per thread (512B contiguous per 2 rows
    // per instruction).
    float4 va[8];
    #pragma unroll
    for (int it = 0; it < 8; ++it) {
        int idx = it * 256 + t;          // 0..2047
        int m   = idx >> 5;              // row 0..63
        int k4  = (idx & 31) << 2;       // float col, multiple of 4
        va[it] = *reinterpret_cast<const float4*>(Ab + (size_t)m * 4096 + k4);
    }
    // W tile 64x128 f32, read column-wise for transpose: 32 scalar dwords per
    // thread; each instruction's wave footprint is 256B contiguous along n.
    const int n  = t & 127;
    const int c0 = (t >> 7) << 2;        // 0 or 4
    float wv[32];
    #pragma unroll
    for (int it = 0; it < 8; ++it) {
        int c = it * 8 + c0;
        #pragma unroll
        for (int r = 0; r < 4; ++r)
            wv[it * 4 + r] = Wb[(size_t)(c + r) * 4096 + n];
    }

    // ================= Phase 2: convert + LDS writes (vmcnt counts down)
    #pragma unroll
    for (int it = 0; it < 8; ++it) {
        int idx = it * 256 + t;
        int m   = idx >> 5;
        int k4  = (idx & 31) << 2;
        unsigned long long pk =
            (unsigned long long)f2bf(va[it].x)         |
            ((unsigned long long)f2bf(va[it].y) << 16) |
            ((unsigned long long)f2bf(va[it].z) << 32) |
            ((unsigned long long)f2bf(va[it].w) << 48);
        int addr = m * 256 + ((k4 * 2) ^ ((m & 7) << 4));
        *reinterpret_cast<unsigned long long*>(smem + addr) = pk;
    }
    #pragma unroll
    for (int it = 0; it < 8; ++it) {
        int c = it * 8 + c0;
        unsigned long long pk =
            (unsigned long long)f2bf(wv[it * 4 + 0])         |
            ((unsigned long long)f2bf(wv[it * 4 + 1]) << 16) |
            ((unsigned long long)f2bf(wv[it * 4 + 2]) << 32) |
            ((unsigned long long)f2bf(wv[it * 4 + 3]) << 48);
        int addr = n * 128 + ((c * 2) ^ ((n & 7) << 4));
        *reinterpret_cast<unsigned long long*>(
            reinterpret_cast<char*>(Ws) + addr) = pk;
    }

    __syncthreads();

    // ================= MFMA: 4 waves; wave wv owns rows [wv*16, +16) x 128.
    // Per block jj in {0,1}: out_jj = A[:, jj*64..] @ W_jj (contract c=0..63).
    const int l  = t & 63;
    const int wvid = t >> 6;
    const int lr = l & 15;
    const int lk = l >> 4;

    f32x4 acc[8];
    #pragma unroll
    for (int z = 0; z < 8; ++z) acc[z] = (f32x4){0.f, 0.f, 0.f, 0.f};

    const int am = wvid * 16 + lr;
    #pragma unroll
    for (int jj = 0; jj < 2; ++jj) {
        #pragma unroll
        for (int kt = 0; kt < 2; ++kt) {
            int kbA = jj * 128 + kt * 64 + lk * 16;    // byte col in As row
            bf16x8 af = *reinterpret_cast<const bf16x8*>(
                smem + am * 256 + (kbA ^ ((am & 7) << 4)));
            int kbB = kt * 64 + lk * 16;               // byte col in Ws row
            #pragma unroll
            for (int nt = 0; nt < 4; ++nt) {
                int bn = jj * 64 + nt * 16 + lr;
                bf16x8 bfr = *reinterpret_cast<const bf16x8*>(
                    reinterpret_cast<const char*>(Ws) + bn * 128 +
                    (kbB ^ ((bn & 7) << 4)));
                acc[jj * 4 + nt] =
                    __builtin_amdgcn_mfma_f32_16x16x32_bf16(af, bfr,
                                                            acc[jj * 4 + nt],
                                                            0, 0, 0);
            }
        }
    }

    // ================= Epilogue: bounce acc through LDS (aliases As/Ws) to
    // emit dwordx4 stores (512B contiguous per 2 rows per instruction).
    __syncthreads();    // all MFMA LDS reads done before overwrite

    #pragma unroll
    for (int fn = 0; fn < 8; ++fn) {
        #pragma unroll
        for (int r = 0; r < 4; ++r) {
            int row = wvid * 16 + lk * 4 + r;
            int col = fn * 16 + lr;
            Os[row * 128 + (col ^ ((row & 7) << 2))] = acc[fn][r];
        }
    }

    __syncthreads();

    #pragma unroll
    for (int it = 0; it < 8; ++it) {
        int idx = it * 256 + t;
        int row = idx >> 5;
        int c4  = (idx & 31) << 2;
        int col = c4 ^ ((row & 7) << 2);   // xor of multiples of 4: f32x4 stays aligned
        f32x4 v = *reinterpret_cast<const f32x4*>(Os + row * 128 + col);
        *reinterpret_cast<f32x4*>(Ob + (size_t)row * 4096 + c4) = v;
    }
}

extern "C" void kernel_launch(void* const* d_in, const int* in_sizes, int n_in,
                              void* d_out, int out_size, void* d_ws, size_t ws_size,
                              hipStream_t stream) {
    const float* x = (const float*)d_in[0];   // [4, 4096, 4096] fp32
    const float* w = (const float*)d_in[1];   // [4096, 4096] fp32
    float* out = (float*)d_out;               // [4, 4096, 4096] fp32

    dim3 grid(8192);
    dim3 block(256);
    block_matmul_kernel<<<grid, block, 0, stream>>>(x, w, out);
}